// Round 10
// baseline (218.494 us; speedup 1.0000x reference)
//
#include <hip/hip_runtime.h>

typedef unsigned short ushort_t;
typedef __attribute__((ext_vector_type(8))) unsigned short ushort8;
typedef __attribute__((ext_vector_type(8))) __bf16 bf16x8;  // MFMA A/B frag
typedef __attribute__((ext_vector_type(4))) float f32x4;    // MFMA C/D frag

#define CAP 128   // per-node bucket capacity (max degree ~35 for Poisson(12), N=50k)
#define BN 32     // node tile per block

__device__ __forceinline__ ushort_t f2bf(float f) {
    union { float f; unsigned u; } v; v.f = f;
    unsigned r = v.u + 0x7FFFu + ((v.u >> 16) & 1u);   // RNE
    return (ushort_t)(r >> 16);
}
__device__ __forceinline__ float bf2f(ushort_t b) {
    union { unsigned u; float f; } v; v.u = ((unsigned)b) << 16;
    return v.f;
}

// ---------------- prep: conv x (f32->bf16) + conv W (both layers) + zero cnt ----
__global__ __launch_bounds__(256) void prep_kernel(
    const float* __restrict__ x, ushort_t* __restrict__ xb,
    const float* __restrict__ W1l, const float* __restrict__ W1r,
    const float* __restrict__ W2l, const float* __restrict__ W2r,
    ushort_t* __restrict__ WT1, ushort_t* __restrict__ WT2,
    int* __restrict__ cnt, int n8, int n)
{
    int gid = blockIdx.x * 256 + threadIdx.x;
    if (gid < n) cnt[gid] = 0;
    if (gid < 65536) {   // weight transpose-convert: WT[c][k]
        int layer = gid >> 15;
        int id = gid & 32767;
        int k = id >> 7;
        int c = id & 127;
        const float* Wl = layer ? W2l : W1l;
        const float* Wr = layer ? W2r : W1r;
        ushort_t* WT = layer ? WT2 : WT1;
        float v = (k < 128) ? Wl[(size_t)k * 128 + c] : Wr[(size_t)(k - 128) * 128 + c];
        WT[(size_t)c * 256 + k] = f2bf(v);
    }
    if (gid >= n8) return;
    const float4 v0 = *(const float4*)&x[(size_t)gid * 8];
    const float4 v1 = *(const float4*)&x[(size_t)gid * 8 + 4];
    ushort8 r;
    r[0] = f2bf(v0.x); r[1] = f2bf(v0.y); r[2] = f2bf(v0.z); r[3] = f2bf(v0.w);
    r[4] = f2bf(v1.x); r[5] = f2bf(v1.y); r[6] = f2bf(v1.z); r[7] = f2bf(v1.w);
    *(ushort8*)&xb[(size_t)gid * 8] = r;
}

// ---------------- bucket fill: esrc[dst*CAP + pos] = src; cnt[dst] = degree ----
__global__ __launch_bounds__(256) void fill_bucket(
    const int* __restrict__ src, const int* __restrict__ dst,
    int* __restrict__ cnt, int* __restrict__ esrc, int E)
{
    int e = blockIdx.x * 256 + threadIdx.x;
    if (e < E) {
        int d = dst[e];
        int pos = atomicAdd(&cnt[d], 1);
        if (pos < CAP) esrc[(size_t)d * CAP + pos] = src[e];
    }
}

// ---------------- fused SAGE layer: out = act([mean|feat] @ WT^T + b) ----------
// block = 256 thr (4 waves), tile = 32 nodes. Wave w gathers nodes w*8..w*8+7;
// 64 lanes = 4 slots x 16 cols; slot s loads its own int4 of edge indices
// (same-address broadcast). First-chunk (d<=16) idx prefetched for all 8 nodes.
__global__ __launch_bounds__(256) void sage_layer(
    const ushort_t* __restrict__ feat,  // [n][128] bf16 (xb or h1b)
    const int* __restrict__ esrc,       // [n][CAP]
    const int* __restrict__ cnt,        // [n] degrees
    const ushort_t* __restrict__ WT,    // [128][256]
    const float* __restrict__ bias,     // [128]
    ushort_t* __restrict__ out_b,       // bf16 out (layer1) or null
    float* __restrict__ out_f,          // f32 out (layer2) or null
    int n, int do_relu)
{
    __shared__ __align__(16) ushort_t a_lds[BN * 256];   // 16 KB

    const int t = threadIdx.x;
    const int tile = blockIdx.x * BN;
    const int w = t >> 6;
    const int l = t & 63;
    const int l15 = l & 15;
    const int lg = l >> 4;   // 0..3
    const int slot = lg;
    const int c = l15 << 3;  // col base (8 bf16 per lane)

    // --- Phase A: stage feat rows into granules 16..31 (x-side of concat) ---
#pragma unroll
    for (int j = 0; j < 2; ++j) {
        int idx = t + j * 256;     // 0..511
        int r = idx >> 4;          // 0..31
        int g16 = idx & 15;
        int gr = tile + r;
        ushort8 v = (ushort8)0;
        if (gr < n) v = *(const ushort8*)&feat[(size_t)gr * 128 + g16 * 8];
        int dstb = r * 512 + (((16 + g16) * 16) ^ ((r & 7) << 4));
        *(ushort8*)((char*)a_lds + dstb) = v;
    }

    // --- Phase B: gather means for nodes w*8..w*8+7 into granules 0..15 ---
    const int nbase = tile + w * 8;
    // degree prefetch (one load per 8 nodes)
    int dv = 0;
    if (l < 8 && nbase + l < n) dv = cnt[nbase + l];

    // first-chunk idx prefetch for all 8 nodes (covers d<=16)
    int4 iv[8];
#pragma unroll
    for (int i = 0; i < 8; ++i) {
        if (nbase + i < n)
            iv[i] = *(const int4*)(esrc + (size_t)(nbase + i) * CAP + slot * 4);
    }

#pragma unroll
    for (int i = 0; i < 8; ++i) {
        int node = nbase + i;
        if (node >= n) break;   // wave-uniform
        int d = min(__shfl(dv, i, 64), CAP);
        const int* bp = esrc + (size_t)node * CAP;

        float a[8];
#pragma unroll
        for (int j = 0; j < 8; ++j) a[j] = 0.f;

        // chunk 0 from prefetched iv[i]
        if (slot * 4 < d) {
            int e0 = slot * 4;
            int s0 = iv[i].x;
            int s1 = (e0 + 1 < d) ? iv[i].y : s0;
            int s2 = (e0 + 2 < d) ? iv[i].z : s0;
            int s3 = (e0 + 3 < d) ? iv[i].w : s0;
            ushort8 r0 = *(const ushort8*)&feat[(size_t)s0 * 128 + c];
            ushort8 r1 = *(const ushort8*)&feat[(size_t)s1 * 128 + c];
            ushort8 r2 = *(const ushort8*)&feat[(size_t)s2 * 128 + c];
            ushort8 r3 = *(const ushort8*)&feat[(size_t)s3 * 128 + c];
#pragma unroll
            for (int j = 0; j < 8; ++j) a[j] += bf2f(r0[j]);
            if (e0 + 1 < d) {
#pragma unroll
                for (int j = 0; j < 8; ++j) a[j] += bf2f(r1[j]);
            }
            if (e0 + 2 < d) {
#pragma unroll
                for (int j = 0; j < 8; ++j) a[j] += bf2f(r2[j]);
            }
            if (e0 + 3 < d) {
#pragma unroll
                for (int j = 0; j < 8; ++j) a[j] += bf2f(r3[j]);
            }
        }
        // rare chunks (d > 16)
        for (int cb = 16; cb < d; cb += 16) {
            int e0 = cb + slot * 4;
            if (e0 < d) {
                int4 v2 = *(const int4*)(bp + e0);
                int s0 = v2.x;
                int s1 = (e0 + 1 < d) ? v2.y : s0;
                int s2 = (e0 + 2 < d) ? v2.z : s0;
                int s3 = (e0 + 3 < d) ? v2.w : s0;
                ushort8 r0 = *(const ushort8*)&feat[(size_t)s0 * 128 + c];
                ushort8 r1 = *(const ushort8*)&feat[(size_t)s1 * 128 + c];
                ushort8 r2 = *(const ushort8*)&feat[(size_t)s2 * 128 + c];
                ushort8 r3 = *(const ushort8*)&feat[(size_t)s3 * 128 + c];
#pragma unroll
                for (int j = 0; j < 8; ++j) a[j] += bf2f(r0[j]);
                if (e0 + 1 < d) {
#pragma unroll
                    for (int j = 0; j < 8; ++j) a[j] += bf2f(r1[j]);
                }
                if (e0 + 2 < d) {
#pragma unroll
                    for (int j = 0; j < 8; ++j) a[j] += bf2f(r2[j]);
                }
                if (e0 + 3 < d) {
#pragma unroll
                    for (int j = 0; j < 8; ++j) a[j] += bf2f(r3[j]);
                }
            }
        }

        // cross-slot reduce (all lanes participate)
#pragma unroll
        for (int j = 0; j < 8; ++j) {
            a[j] += __shfl_xor(a[j], 16, 64);
            a[j] += __shfl_xor(a[j], 32, 64);
        }

        if (slot == 0) {
            float sc = 1.0f / fmaxf((float)d, 1.0f);
            ushort8 rv;
#pragma unroll
            for (int j = 0; j < 8; ++j) rv[j] = f2bf(a[j] * sc);
            int r = w * 8 + i;
            int dstb = r * 512 + ((l15 * 16) ^ ((r & 7) << 4));
            *(ushort8*)((char*)a_lds + dstb) = rv;
        }
    }
    __syncthreads();

    // --- Phase C: B fragments from L2-resident WT, then MFMA ---
    bf16x8 bfrag[2][8];
    {
        const ushort_t* p0 = &WT[(size_t)(w * 32 + l15) * 256 + lg * 8];
        const ushort_t* p1 = p0 + 16 * 256;
#pragma unroll
        for (int ks = 0; ks < 8; ++ks) {
            bfrag[0][ks] = *(const bf16x8*)(p0 + ks * 32);
            bfrag[1][ks] = *(const bf16x8*)(p1 + ks * 32);
        }
    }

    f32x4 acc[2][2];
#pragma unroll
    for (int rt = 0; rt < 2; ++rt)
#pragma unroll
        for (int ct = 0; ct < 2; ++ct)
#pragma unroll
            for (int i = 0; i < 4; ++i) acc[rt][ct][i] = 0.f;

#pragma unroll
    for (int ks = 0; ks < 8; ++ks) {
        bf16x8 af[2];
#pragma unroll
        for (int rt = 0; rt < 2; ++rt) {
            int r = rt * 16 + l15;
            int byteoff = r * 512 + (((ks * 64) + lg * 16) ^ ((r & 7) << 4));
            af[rt] = *(const bf16x8*)((const char*)a_lds + byteoff);
        }
#pragma unroll
        for (int rt = 0; rt < 2; ++rt)
#pragma unroll
            for (int ct = 0; ct < 2; ++ct)
                acc[rt][ct] = __builtin_amdgcn_mfma_f32_16x16x32_bf16(
                    af[rt], bfrag[ct][ks], acc[rt][ct], 0, 0, 0);
    }

    // --- epilogue: C/D layout col = lane&15, row = (lane>>4)*4 + reg ---
#pragma unroll
    for (int ct = 0; ct < 2; ++ct) {
        int col = w * 32 + ct * 16 + l15;
        float bv = bias[col];
#pragma unroll
        for (int rt = 0; rt < 2; ++rt) {
#pragma unroll
            for (int i = 0; i < 4; ++i) {
                int row = tile + rt * 16 + lg * 4 + i;
                if (row < n) {
                    float v = acc[rt][ct][i] + bv;
                    if (do_relu) v = fmaxf(v, 0.f);
                    if (out_b) out_b[(size_t)row * 128 + col] = f2bf(v);
                    else       out_f[(size_t)row * 128 + col] = v;
                }
            }
        }
    }
}

extern "C" void kernel_launch(void* const* d_in, const int* in_sizes, int n_in,
                              void* d_out, int out_size, void* d_ws, size_t ws_size,
                              hipStream_t stream) {
    const float* x   = (const float*)d_in[0];
    const int*   ei  = (const int*)d_in[1];
    const float* W1l = (const float*)d_in[2];
    const float* b1l = (const float*)d_in[3];
    const float* W1r = (const float*)d_in[4];
    const float* W2l = (const float*)d_in[5];
    const float* b2l = (const float*)d_in[6];
    const float* W2r = (const float*)d_in[7];
    float* out = (float*)d_out;

    const int N = in_sizes[0] / 128;   // 50000
    const int E = in_sizes[1] / 2;     // 600000
    const int* src = ei;
    const int* dst = ei + E;

    char* ws = (char*)d_ws;
    ushort_t* xb  = (ushort_t*)ws;  ws += (size_t)N * 128 * sizeof(ushort_t);
    ushort_t* h1b = (ushort_t*)ws;  ws += (size_t)N * 128 * sizeof(ushort_t);
    ushort_t* WT1 = (ushort_t*)ws;  ws += 32768 * sizeof(ushort_t);
    ushort_t* WT2 = (ushort_t*)ws;  ws += 32768 * sizeof(ushort_t);
    int* cnt  = (int*)ws;  ws += (size_t)N * sizeof(int);
    int* esrc = (int*)ws;  ws += (size_t)N * CAP * sizeof(int);

    // ---- prep: conversions + cnt zeroing ----
    const int n8 = N * 128 / 8;   // 800000
    prep_kernel<<<(n8 + 255) / 256, 256, 0, stream>>>(x, xb, W1l, W1r, W2l, W2r,
                                                      WT1, WT2, cnt, n8, N);

    // ---- bucket fill (replaces count+scan+fill) ----
    fill_bucket<<<(E + 255) / 256, 256, 0, stream>>>(src, dst, cnt, esrc, E);

    const int nblk = (N + BN - 1) / BN;   // 1563

    // ---- layer 1 (fused gather+linear), writes h1b ----
    sage_layer<<<nblk, 256, 0, stream>>>(xb, esrc, cnt, WT1, b1l, h1b, nullptr, N, 1);

    // ---- layer 2, writes f32 out ----
    sage_layer<<<nblk, 256, 0, stream>>>(h1b, esrc, cnt, WT2, b2l, nullptr, out, N, 0);
}

// Round 11
// 198.623 us; speedup vs baseline: 1.1000x; 1.1000x over previous
//
#include <hip/hip_runtime.h>

typedef unsigned short ushort_t;
typedef __attribute__((ext_vector_type(8))) unsigned short ushort8;
typedef __attribute__((ext_vector_type(8))) __bf16 bf16x8;  // MFMA A/B frag
typedef __attribute__((ext_vector_type(4))) float f32x4;    // MFMA C/D frag

#define CAP 128   // per-node bucket capacity (max degree ~36 for Poisson(12), N=50k)
#define BN 32     // node tile per block

__device__ __forceinline__ ushort_t f2bf(float f) {
    union { float f; unsigned u; } v; v.f = f;
    unsigned r = v.u + 0x7FFFu + ((v.u >> 16) & 1u);   // RNE
    return (ushort_t)(r >> 16);
}
__device__ __forceinline__ float bf2f(ushort_t b) {
    union { unsigned u; float f; } v; v.u = ((unsigned)b) << 16;
    return v.f;
}

// ---------------- prep: conv x (f32->bf16) + conv W (both layers) + zero cnt ----
__global__ __launch_bounds__(256) void prep_kernel(
    const float* __restrict__ x, ushort_t* __restrict__ xb,
    const float* __restrict__ W1l, const float* __restrict__ W1r,
    const float* __restrict__ W2l, const float* __restrict__ W2r,
    ushort_t* __restrict__ WT1, ushort_t* __restrict__ WT2,
    int* __restrict__ cnt, int n8, int n)
{
    int gid = blockIdx.x * 256 + threadIdx.x;
    if (gid < n) cnt[gid] = 0;
    if (gid < 65536) {   // weight transpose-convert: WT[c][k]
        int layer = gid >> 15;
        int id = gid & 32767;
        int k = id >> 7;
        int c = id & 127;
        const float* Wl = layer ? W2l : W1l;
        const float* Wr = layer ? W2r : W1r;
        ushort_t* WT = layer ? WT2 : WT1;
        float v = (k < 128) ? Wl[(size_t)k * 128 + c] : Wr[(size_t)(k - 128) * 128 + c];
        WT[(size_t)c * 256 + k] = f2bf(v);
    }
    if (gid >= n8) return;
    const float4 v0 = *(const float4*)&x[(size_t)gid * 8];
    const float4 v1 = *(const float4*)&x[(size_t)gid * 8 + 4];
    ushort8 r;
    r[0] = f2bf(v0.x); r[1] = f2bf(v0.y); r[2] = f2bf(v0.z); r[3] = f2bf(v0.w);
    r[4] = f2bf(v1.x); r[5] = f2bf(v1.y); r[6] = f2bf(v1.z); r[7] = f2bf(v1.w);
    *(ushort8*)&xb[(size_t)gid * 8] = r;
}

// ---------------- bucket fill: esrc[dst*CAP + pos] = src; cnt[dst] = degree ----
__global__ __launch_bounds__(256) void fill_bucket(
    const int* __restrict__ src, const int* __restrict__ dst,
    int* __restrict__ cnt, int* __restrict__ esrc, int E)
{
    int e = blockIdx.x * 256 + threadIdx.x;
    if (e < E) {
        int d = dst[e];
        int pos = atomicAdd(&cnt[d], 1);
        if (pos < CAP) esrc[(size_t)d * CAP + pos] = src[e];
    }
}

// ---------------- fused SAGE layer: out = act([mean|feat] @ WT^T + b) ----------
// block = 256 thr (4 waves), tile = 32 nodes.
// Phase B: slot-per-node — each 16-lane slot owns one node entirely
// (16 lanes x 8 bf16 = full 128-col row per edge). No shfl at all.
// 4 concurrent per-node chains per wave x 2 rounds. Idx loads are
// slot-uniform (HW broadcast); next-chunk idx prefetched.
__global__ __launch_bounds__(256) void sage_layer(
    const ushort_t* __restrict__ feat,  // [n][128] bf16 (xb or h1b)
    const int* __restrict__ esrc,       // [n][CAP]
    const int* __restrict__ cnt,        // [n] degrees
    const ushort_t* __restrict__ WT,    // [128][256]
    const float* __restrict__ bias,     // [128]
    ushort_t* __restrict__ out_b,       // bf16 out (layer1) or null
    float* __restrict__ out_f,          // f32 out (layer2) or null
    int n, int do_relu)
{
    __shared__ __align__(16) ushort_t a_lds[BN * 256];   // 16 KB

    const int t = threadIdx.x;
    const int tile = blockIdx.x * BN;
    const int w = t >> 6;
    const int l = t & 63;
    const int l15 = l & 15;
    const int lg = l >> 4;   // 0..3 (slot)
    const int c = l15 << 3;  // col base (8 bf16 per lane)

    // --- Phase A: stage feat rows into granules 16..31 (x-side of concat) ---
#pragma unroll
    for (int j = 0; j < 2; ++j) {
        int idx = t + j * 256;     // 0..511
        int r = idx >> 4;          // 0..31
        int g16 = idx & 15;
        int gr = tile + r;
        ushort8 v = (ushort8)0;
        if (gr < n) v = *(const ushort8*)&feat[(size_t)gr * 128 + g16 * 8];
        int dstb = r * 512 + (((16 + g16) * 16) ^ ((r & 7) << 4));
        *(ushort8*)((char*)a_lds + dstb) = v;
    }

    // --- Phase B: slot-per-node gather, 2 rounds of 4 nodes per wave ---
    const int r0_ = w * 8 + lg;        // local rows for this slot
    const int r1_ = r0_ + 4;
    const int node0 = tile + r0_;
    const int node1 = tile + r1_;
    const int* bp0 = esrc + (size_t)node0 * CAP;
    const int* bp1 = esrc + (size_t)node1 * CAP;
    // prefetch degrees + first idx chunks for both rounds (slot-uniform loads)
    int d0 = (node0 < n) ? min(cnt[node0], CAP) : 0;
    int d1 = (node1 < n) ? min(cnt[node1], CAP) : 0;
    int4 q0, q1;
    if (d0 > 0) q0 = *(const int4*)bp0;
    if (d1 > 0) q1 = *(const int4*)bp1;

#define GATHER_NODE(rloc, dd, bp, qfirst)                                       \
    {                                                                           \
        float a[8];                                                             \
        _Pragma("unroll")                                                       \
        for (int j = 0; j < 8; ++j) a[j] = 0.f;                                 \
        int4 q = qfirst;                                                        \
        for (int cb = 0; cb < dd; cb += 4) {                                    \
            int4 qn;                                                            \
            if (cb + 4 < dd) qn = *(const int4*)((bp) + cb + 4);                \
            int s0 = q.x;                                                       \
            int s1 = (cb + 1 < dd) ? q.y : s0;                                  \
            int s2 = (cb + 2 < dd) ? q.z : s0;                                  \
            int s3 = (cb + 3 < dd) ? q.w : s0;                                  \
            ushort8 v0 = *(const ushort8*)&feat[(size_t)s0 * 128 + c];          \
            ushort8 v1 = *(const ushort8*)&feat[(size_t)s1 * 128 + c];          \
            ushort8 v2 = *(const ushort8*)&feat[(size_t)s2 * 128 + c];          \
            ushort8 v3 = *(const ushort8*)&feat[(size_t)s3 * 128 + c];          \
            _Pragma("unroll")                                                   \
            for (int j = 0; j < 8; ++j) a[j] += bf2f(v0[j]);                    \
            if (cb + 1 < dd) {                                                  \
                _Pragma("unroll")                                               \
                for (int j = 0; j < 8; ++j) a[j] += bf2f(v1[j]);                \
            }                                                                   \
            if (cb + 2 < dd) {                                                  \
                _Pragma("unroll")                                               \
                for (int j = 0; j < 8; ++j) a[j] += bf2f(v2[j]);                \
            }                                                                   \
            if (cb + 3 < dd) {                                                  \
                _Pragma("unroll")                                               \
                for (int j = 0; j < 8; ++j) a[j] += bf2f(v3[j]);                \
            }                                                                   \
            q = qn;                                                             \
        }                                                                       \
        if (tile + (rloc) < n) {                                                \
            float sc = 1.0f / fmaxf((float)(dd), 1.0f);                         \
            ushort8 rv;                                                         \
            _Pragma("unroll")                                                   \
            for (int j = 0; j < 8; ++j) rv[j] = f2bf(a[j] * sc);                \
            int dstb = (rloc) * 512 + ((l15 * 16) ^ (((rloc) & 7) << 4));       \
            *(ushort8*)((char*)a_lds + dstb) = rv;                              \
        }                                                                       \
    }

    GATHER_NODE(r0_, d0, bp0, q0)
    GATHER_NODE(r1_, d1, bp1, q1)
#undef GATHER_NODE

    __syncthreads();

    // --- Phase C: B fragments from L2-resident WT, then MFMA ---
    bf16x8 bfrag[2][8];
    {
        const ushort_t* p0 = &WT[(size_t)(w * 32 + l15) * 256 + lg * 8];
        const ushort_t* p1 = p0 + 16 * 256;
#pragma unroll
        for (int ks = 0; ks < 8; ++ks) {
            bfrag[0][ks] = *(const bf16x8*)(p0 + ks * 32);
            bfrag[1][ks] = *(const bf16x8*)(p1 + ks * 32);
        }
    }

    f32x4 acc[2][2];
#pragma unroll
    for (int rt = 0; rt < 2; ++rt)
#pragma unroll
        for (int ct = 0; ct < 2; ++ct)
#pragma unroll
            for (int i = 0; i < 4; ++i) acc[rt][ct][i] = 0.f;

#pragma unroll
    for (int ks = 0; ks < 8; ++ks) {
        bf16x8 af[2];
#pragma unroll
        for (int rt = 0; rt < 2; ++rt) {
            int r = rt * 16 + l15;
            int byteoff = r * 512 + (((ks * 64) + lg * 16) ^ ((r & 7) << 4));
            af[rt] = *(const bf16x8*)((const char*)a_lds + byteoff);
        }
#pragma unroll
        for (int rt = 0; rt < 2; ++rt)
#pragma unroll
            for (int ct = 0; ct < 2; ++ct)
                acc[rt][ct] = __builtin_amdgcn_mfma_f32_16x16x32_bf16(
                    af[rt], bfrag[ct][ks], acc[rt][ct], 0, 0, 0);
    }

    // --- epilogue: C/D layout col = lane&15, row = (lane>>4)*4 + reg ---
#pragma unroll
    for (int ct = 0; ct < 2; ++ct) {
        int col = w * 32 + ct * 16 + l15;
        float bv = bias[col];
#pragma unroll
        for (int rt = 0; rt < 2; ++rt) {
#pragma unroll
            for (int i = 0; i < 4; ++i) {
                int row = tile + rt * 16 + lg * 4 + i;
                if (row < n) {
                    float v = acc[rt][ct][i] + bv;
                    if (do_relu) v = fmaxf(v, 0.f);
                    if (out_b) out_b[(size_t)row * 128 + col] = f2bf(v);
                    else       out_f[(size_t)row * 128 + col] = v;
                }
            }
        }
    }
}

extern "C" void kernel_launch(void* const* d_in, const int* in_sizes, int n_in,
                              void* d_out, int out_size, void* d_ws, size_t ws_size,
                              hipStream_t stream) {
    const float* x   = (const float*)d_in[0];
    const int*   ei  = (const int*)d_in[1];
    const float* W1l = (const float*)d_in[2];
    const float* b1l = (const float*)d_in[3];
    const float* W1r = (const float*)d_in[4];
    const float* W2l = (const float*)d_in[5];
    const float* b2l = (const float*)d_in[6];
    const float* W2r = (const float*)d_in[7];
    float* out = (float*)d_out;

    const int N = in_sizes[0] / 128;   // 50000
    const int E = in_sizes[1] / 2;     // 600000
    const int* src = ei;
    const int* dst = ei + E;

    char* ws = (char*)d_ws;
    ushort_t* xb  = (ushort_t*)ws;  ws += (size_t)N * 128 * sizeof(ushort_t);
    ushort_t* h1b = (ushort_t*)ws;  ws += (size_t)N * 128 * sizeof(ushort_t);
    ushort_t* WT1 = (ushort_t*)ws;  ws += 32768 * sizeof(ushort_t);
    ushort_t* WT2 = (ushort_t*)ws;  ws += 32768 * sizeof(ushort_t);
    int* cnt  = (int*)ws;  ws += (size_t)N * sizeof(int);
    int* esrc = (int*)ws;  ws += (size_t)N * CAP * sizeof(int);

    // ---- prep: conversions + cnt zeroing ----
    const int n8 = N * 128 / 8;   // 800000
    prep_kernel<<<(n8 + 255) / 256, 256, 0, stream>>>(x, xb, W1l, W1r, W2l, W2r,
                                                      WT1, WT2, cnt, n8, N);

    // ---- bucket fill (replaces count+scan+fill) ----
    fill_bucket<<<(E + 255) / 256, 256, 0, stream>>>(src, dst, cnt, esrc, E);

    const int nblk = (N + BN - 1) / BN;   // 1563

    // ---- layer 1 (fused gather+linear), writes h1b ----
    sage_layer<<<nblk, 256, 0, stream>>>(xb, esrc, cnt, WT1, b1l, h1b, nullptr, N, 1);

    // ---- layer 2, writes f32 out ----
    sage_layer<<<nblk, 256, 0, stream>>>(h1b, esrc, cnt, WT2, b2l, nullptr, out, N, 0);
}